// Round 1
// baseline (131.170 us; speedup 1.0000x reference)
//
#include <hip/hip_runtime.h>
#include <hip/hip_bf16.h>
#include <math.h>

// Problem constants
#define BATCH   2048
#define TWO_B   4096
#define DIM     1024
// 1 / (0.07 * ln(2)) : exp(s/T) = exp2(s * INV_T_LOG2E)
#define INV_T_LOG2E 20.60991907f
#define INV_T       14.285714285714286f

typedef __bf16  bf16x8 __attribute__((ext_vector_type(8)));
typedef float   f32x4  __attribute__((ext_vector_type(4)));

__device__ __forceinline__ unsigned short f2bf(float f) {
    union { float f; unsigned int u; } x; x.f = f;
    unsigned int u = x.u;
    return (unsigned short)((u + 0x7fffu + ((u >> 16) & 1u)) >> 16); // RNE
}

__device__ __forceinline__ void load_lds16(const void* g, void* l) {
    __builtin_amdgcn_global_load_lds(
        (const __attribute__((address_space(1))) void*)g,
        (__attribute__((address_space(3))) void*)l,
        16, 0, 0);
}

// ---------------------------------------------------------------------------
// Kernel 1: L2-normalize each of the 4096 rows, write bf16 z[4096][1024].
// Row r < 2048 -> features[r, 0, :], r >= 2048 -> features[r-2048, 1, :].
// ---------------------------------------------------------------------------
__global__ __launch_bounds__(256) void normalize_kernel(
        const float* __restrict__ feat, unsigned short* __restrict__ z) {
    const int row = blockIdx.x;
    const int tid = threadIdx.x;
    const float* src = feat + (row < BATCH ? (size_t)row * (2 * DIM)
                                           : (size_t)(row - BATCH) * (2 * DIM) + DIM);
    float4 v = ((const float4*)src)[tid];
    float ss = v.x * v.x + v.y * v.y + v.z * v.z + v.w * v.w;
    #pragma unroll
    for (int off = 32; off; off >>= 1) ss += __shfl_down(ss, off, 64);
    __shared__ float s_part[4];
    if ((tid & 63) == 0) s_part[tid >> 6] = ss;
    __syncthreads();
    float total = s_part[0] + s_part[1] + s_part[2] + s_part[3];
    float scale = 1.0f / fmaxf(sqrtf(total), 1e-12f);
    ushort4 o;
    o.x = f2bf(v.x * scale);
    o.y = f2bf(v.y * scale);
    o.z = f2bf(v.z * scale);
    o.w = f2bf(v.w * scale);
    ((ushort4*)(z + (size_t)row * DIM))[tid] = o;
}

// ---------------------------------------------------------------------------
// Kernel 2: fused sim = z z^T (bf16 MFMA, 128x128 tile, BK=32) + epilogue:
//   rowsum[r] += sum_{c != r} exp(sim[r,c]/T)   (atomicAdd, fp32)
//   positives[r] = sim[r, (r+2048) & 4095]
// m97 structure: global_load_lds width=16 staging, 2-barrier K-loop,
// 4 waves each computing a 64x64 subtile as 4x4 MFMA_16x16x32_bf16.
// ---------------------------------------------------------------------------
__global__ __launch_bounds__(256) void gemm_fused(
        const unsigned short* __restrict__ z,
        float* __restrict__ rowsum,
        float* __restrict__ positives) {
    __shared__ __bf16 sA[128 * 32];
    __shared__ __bf16 sB[128 * 32];

    const int tid  = threadIdx.x;
    const int lane = tid & 63;
    const int wv   = tid >> 6;       // wave 0..3
    const int wr   = wv >> 1;        // wave row (0..1) -> 64-row subtile
    const int wc   = wv & 1;         // wave col (0..1) -> 64-col subtile
    const int q    = lane >> 4;      // quad 0..3
    const int mn   = lane & 15;      // m (A) / n (B) index
    const int rb   = blockIdx.y * 128;
    const int cb   = blockIdx.x * 128;

    f32x4 acc[4][4] = {};

    const char* zb   = (const char*)z;        // row stride = 2048 bytes
    const int ci0    = wv * 2;                // this wave's 2 staging chunks
    const int lrow   = lane >> 2;             // row within 16-row chunk
    const int lcolb  = (lane & 3) * 16;       // byte offset along K

    for (int k0 = 0; k0 < DIM; k0 += 32) {
        #pragma unroll
        for (int t = 0; t < 2; ++t) {
            const int ci = ci0 + t;           // chunk 0..7, 16 rows each
            const char* gA = zb + (size_t)(rb + ci * 16 + lrow) * 2048 + k0 * 2 + lcolb;
            const char* gB = zb + (size_t)(cb + ci * 16 + lrow) * 2048 + k0 * 2 + lcolb;
            load_lds16(gA, (char*)sA + ci * 1024);   // lds dest = base + lane*16
            load_lds16(gB, (char*)sB + ci * 1024);
        }
        __syncthreads();

        bf16x8 af[4], bfv[4];
        #pragma unroll
        for (int i = 0; i < 4; ++i) {
            af[i]  = *(const bf16x8*)&sA[(wr * 64 + i * 16 + mn) * 32 + q * 8];
            bfv[i] = *(const bf16x8*)&sB[(wc * 64 + i * 16 + mn) * 32 + q * 8];
        }
        #pragma unroll
        for (int i = 0; i < 4; ++i)
            #pragma unroll
            for (int j = 0; j < 4; ++j)
                acc[i][j] = __builtin_amdgcn_mfma_f32_16x16x32_bf16(
                                af[i], bfv[j], acc[i][j], 0, 0, 0);
        __syncthreads();
    }

    // Epilogue: C/D layout col = lane&15, row = (lane>>4)*4 + reg
    #pragma unroll
    for (int i = 0; i < 4; ++i) {
        #pragma unroll
        for (int reg = 0; reg < 4; ++reg) {
            const int r  = rb + wr * 64 + i * 16 + q * 4 + reg;
            const int pc = (r + BATCH) & (TWO_B - 1);
            float local = 0.0f;
            #pragma unroll
            for (int j = 0; j < 4; ++j) {
                const int c = cb + wc * 64 + j * 16 + mn;
                const float s = acc[i][j][reg];
                if (c == pc) positives[r] = s;
                local += (c == r) ? 0.0f : exp2f(s * INV_T_LOG2E);
            }
            // reduce across the 16 lanes (same q) holding this row's columns
            local += __shfl_xor(local, 1, 64);
            local += __shfl_xor(local, 2, 64);
            local += __shfl_xor(local, 4, 64);
            local += __shfl_xor(local, 8, 64);
            if (mn == 0) atomicAdd(&rowsum[r], local);
        }
    }
}

// ---------------------------------------------------------------------------
// Kernel 3: loss = mean_r( log(rowsum[r]) - positives[r]/T )
// ---------------------------------------------------------------------------
__global__ __launch_bounds__(256) void finalize_kernel(
        const float* __restrict__ rowsum,
        const float* __restrict__ positives,
        float* __restrict__ out) {
    float acc = 0.0f;
    for (int r = threadIdx.x; r < TWO_B; r += 256)
        acc += logf(rowsum[r]) - positives[r] * INV_T;
    #pragma unroll
    for (int off = 32; off; off >>= 1) acc += __shfl_down(acc, off, 64);
    __shared__ float s_part[4];
    if ((threadIdx.x & 63) == 0) s_part[threadIdx.x >> 6] = acc;
    __syncthreads();
    if (threadIdx.x == 0)
        out[0] = (s_part[0] + s_part[1] + s_part[2] + s_part[3]) * (1.0f / TWO_B);
}

extern "C" void kernel_launch(void* const* d_in, const int* in_sizes, int n_in,
                              void* d_out, int out_size, void* d_ws, size_t ws_size,
                              hipStream_t stream) {
    const float* feat = (const float*)d_in[0];
    char* ws = (char*)d_ws;

    // workspace layout: z bf16 [4096][1024] (8 MB) | rowsum f32[4096] | positives f32[4096]
    unsigned short* z  = (unsigned short*)ws;
    float* rowsum      = (float*)(ws + (size_t)TWO_B * DIM * 2);
    float* positives   = rowsum + TWO_B;
    float* out         = (float*)d_out;

    hipMemsetAsync(rowsum, 0, TWO_B * sizeof(float), stream);
    normalize_kernel<<<TWO_B, 256, 0, stream>>>(feat, z);
    gemm_fused<<<dim3(32, 32), 256, 0, stream>>>(z, rowsum, positives);
    finalize_kernel<<<1, 256, 0, stream>>>(rowsum, positives, out);
}